// Round 5
// baseline (366.875 us; speedup 1.0000x reference)
//
#include <hip/hip_runtime.h>
#include <hip/hip_bf16.h>

#define NN 100000
#define EE 1200000
#define F1 128
#define F2 256
#define F3 40
#define MROWS 64
#define NBUK ((NN + 255) / 256)          // 391 coarse buckets (256 nodes each)
#define NBLK 256                         // radix blocks
#define CHUNK ((EE + NBLK - 1) / NBLK)   // 4688 edges per block
#define DCAP 4096                        // max records per bucket (mean 3070, +18 sigma)
#define XB2 ((NN * 32 + 255) / 256)      // 12500 blocks for x-prep (float4 granularity)

typedef __bf16 bf16x8 __attribute__((ext_vector_type(8)));
typedef float  f32x4  __attribute__((ext_vector_type(4)));

__device__ __forceinline__ unsigned short f2bf(float f) {   // RNE bf16
    unsigned u = __float_as_uint(f);
    return (unsigned short)((u + 0x7fffu + ((u >> 16) & 1u)) >> 16);
}
__device__ __forceinline__ float bflo(unsigned v) { return __uint_as_float(v << 16); }
__device__ __forceinline__ float bfhi(unsigned v) { return __uint_as_float(v & 0xffff0000u); }

// ---- pass A: per-(bin,block) coarse histogram only (no global atomics) ----
__global__ __launch_bounds__(256) void k_hist(const int* __restrict__ col,
                                              int* __restrict__ hist,
                                              int* __restrict__ done) {
    if (blockIdx.x == 0 && threadIdx.x == 0) *done = 0;   // for fused scanbin
    __shared__ int lh[NBUK];
    for (int i = threadIdx.x; i < NBUK; i += 256) lh[i] = 0;
    __syncthreads();
    int e0 = blockIdx.x * CHUNK;
    int e1 = min(e0 + CHUNK, EE);
    for (int e = e0 + threadIdx.x; e < e1; e += 256) {
        int c = col[e];
        if ((unsigned)c < (unsigned)NN) atomicAdd(&lh[c >> 8], 1);
    }
    __syncthreads();
    for (int i = threadIdx.x; i < NBUK; i += 256) hist[i * NBLK + blockIdx.x] = lh[i];
}

// ---- pass B (fused B1+B2): per-bin scan; last block scans bin totals ----
__global__ __launch_bounds__(512) void k_scanbin(int* __restrict__ hist,
                                                 int* __restrict__ bintot,
                                                 int* __restrict__ binbase,
                                                 int* __restrict__ done) {
    __shared__ int s[512];
    __shared__ int lastf;
    const int b = blockIdx.x;
    const int tid = threadIdx.x;
    if (tid == 0) lastf = 0;
    int v = (tid < NBLK) ? hist[b * NBLK + tid] : 0;
    s[tid] = v;
    __syncthreads();
    int acc = v;
    for (int d = 1; d < NBLK; d <<= 1) {
        int add = (tid >= d) ? s[tid - d] : 0;
        __syncthreads();
        acc += add;
        s[tid] = acc;
        __syncthreads();
    }
    if (tid < NBLK) hist[b * NBLK + tid] = acc - v;   // exclusive within bin
    if (tid == NBLK - 1) {
        atomicExch(&bintot[b], acc);                  // device-scope publish
        __threadfence();
        if (atomicAdd(done, 1) == NBUK - 1) lastf = 1;  // single-thread release chain
    }
    __syncthreads();
    if (!lastf) return;
    __threadfence();
    // ---- last block: exclusive scan of bin totals -> binbase[NBUK+1] ----
    int w = (tid < NBUK) ? atomicAdd(&bintot[tid], 0) : 0;   // atomic load
    s[tid] = w;
    __syncthreads();
    int a2 = w;
    for (int d = 1; d < 512; d <<= 1) {
        int add = (tid >= d) ? s[tid - d] : 0;
        __syncthreads();
        a2 += add;
        s[tid] = a2;
        __syncthreads();
    }
    if (tid < NBUK) binbase[tid] = a2 - w;
    if (tid == NBUK - 1) binbase[NBUK] = a2;
}

// ---- pass C: scatter records into block-private runs per bin ----
__global__ __launch_bounds__(256) void k_scat(const int* __restrict__ row,
                                              const int* __restrict__ col,
                                              const int* __restrict__ hist,
                                              const int* __restrict__ binbase,
                                              unsigned* __restrict__ rec) {
    __shared__ int lcur[NBUK];
    for (int i = threadIdx.x; i < NBUK; i += 256)
        lcur[i] = binbase[i] + hist[i * NBLK + blockIdx.x];
    __syncthreads();
    int e0 = blockIdx.x * CHUNK;
    int e1 = min(e0 + CHUNK, EE);
    for (int e = e0 + threadIdx.x; e < e1; e += 256) {
        int r = row[e], c = col[e];
        if ((unsigned)c < (unsigned)NN) {
            int pos = atomicAdd(&lcur[c >> 8], 1);   // LDS atomic
            rec[pos] = ((unsigned)r & 0xFFFFFFu) | ((unsigned)(c & 255) << 24);
        }
    }
}

// ---- pass D: bucket -> CSR; derive cnt via LDS histogram; cursor(end) + dinv ----
__global__ __launch_bounds__(256) void k_csr(const int* __restrict__ binbase,
                                             const unsigned* __restrict__ rec,
                                             int* __restrict__ eidx,
                                             int* __restrict__ cnt,
                                             int* __restrict__ cursor,
                                             float* __restrict__ dinv) {
    __shared__ int lcnt[256];
    __shared__ int s[256];
    __shared__ int lcur[256];
    __shared__ int lde[DCAP];
    const int b = blockIdx.x;
    const int tid = threadIdx.x;
    lcnt[tid] = 0;
    __syncthreads();
    const int base = binbase[b];
    const int nb = min(binbase[b + 1] - base, DCAP);
    for (int j = tid; j < nb; j += 256) atomicAdd(&lcnt[rec[base + j] >> 24], 1);
    __syncthreads();
    int cv = lcnt[tid];
    s[tid] = cv;
    __syncthreads();
    int acc = cv;
    for (int d = 1; d < 256; d <<= 1) {
        int add = (tid >= d) ? s[tid - d] : 0;
        __syncthreads();
        acc += add;
        s[tid] = acc;
        __syncthreads();
    }
    int excl = acc - cv;
    lcur[tid] = excl;
    const int node = (b << 8) + tid;
    if (node < NN) {
        cnt[node] = cv;
        cursor[node] = base + excl + cv;            // END cursor (start = end - cnt)
        dinv[node] = rsqrtf((float)(cv + 1));       // +1 self-loop
    }
    __syncthreads();
    for (int j = tid; j < nb; j += 256) {
        unsigned v = rec[base + j];
        int pos = atomicAdd(&lcur[v >> 24], 1);     // LDS atomic
        lde[pos] = (int)(v & 0xFFFFFFu);
    }
    __syncthreads();
    for (int j = tid; j < nb; j += 256) eidx[base + j] = lde[j];
}

// ---- fused prep: xh[i] = bf16(x[i]*dinv[i]) ; pack W1,W2. float4-vectorized ----
__global__ void k_prep(const float4* __restrict__ x, const float* __restrict__ dinv,
                       uint2* __restrict__ xh,
                       const float* __restrict__ W1, const float* __restrict__ W2,
                       __hip_bfloat16* __restrict__ W1p, __hip_bfloat16* __restrict__ W2p) {
    if (blockIdx.x < XB2) {
        int idx = blockIdx.x * 256 + threadIdx.x;   // NN*32 float4s, exact multiple
        float d = dinv[idx >> 5];
        float4 v = x[idx];
        uint2 o;
        o.x = (unsigned)f2bf(v.x * d) | ((unsigned)f2bf(v.y * d) << 16);
        o.y = (unsigned)f2bf(v.z * d) | ((unsigned)f2bf(v.w * d) << 16);
        xh[idx] = o;
    } else {
        int idx = (blockIdx.x - XB2) * 256 + threadIdx.x;
        if (idx < F1 * F2) {
            int k = idx / F2, col = idx - (idx / F2) * F2;
            int k8 = k >> 3, j = k & 7;
            W1p[((size_t)(k8 * F2 + col) << 3) + j] = __float2bfloat16(W1[(size_t)k * F2 + col]);
        } else if (idx < F1 * F2 + F2 * 48) {
            int i2 = idx - F1 * F2;
            int k = i2 / 48, col = i2 - (i2 / 48) * 48;
            int k8 = k >> 3, j = k & 7;
            float v = (col < F3) ? W2[(size_t)k * F3 + col] : 0.0f;
            W2p[((size_t)(k8 * 48 + col) << 3) + j] = __float2bfloat16(v);
        }
    }
}

// ---- FUSED layer-1: per-wave aggregate 16 nodes into LDS, then MFMA GEMM1 +
// ReLU + GEMM2. Each wave touches only its own 16 rows in both GEMMs, so the
// agg buffer (25.6MB write + 25.6MB read) and one launch are eliminated.
// tg MUST NOT overlay xh here (round-4 bug): late blocks still gather from all
// of xh while early blocks write tg. tg lives in the dead rec region instead.
// LDS: ash u32[64][132] (528B rows, 16B-aligned); h overlays it as bf16
// stride 264 (same 528B rows). ----
__global__ __launch_bounds__(256) void k_aggemm(
    const int* __restrict__ cursor, const int* __restrict__ cnt,
    const int* __restrict__ eidx, const float* __restrict__ dinv,
    const unsigned* __restrict__ xh,
    const __hip_bfloat16* __restrict__ W1p, const float* __restrict__ b1,
    const __hip_bfloat16* __restrict__ W2p, unsigned short* __restrict__ tg) {
    __shared__ unsigned ash[MROWS][132];            // 33.8 KB
    const int i0   = blockIdx.x * MROWS;
    const int wave = threadIdx.x >> 6;
    const int lane = threadIdx.x & 63;

    // ---- phase 1: aggregate this wave's 16 nodes (identical math to k_agg1) ----
    for (int j = 0; j < 16; ++j) {
        const int lrow = wave * 16 + j;
        const int node = i0 + lrow;
        if (node >= NN) { ash[lrow][lane] = 0; continue; }
        unsigned vs = xh[((size_t)node << 6) + lane];
        float a0 = bflo(vs), a1 = bfhi(vs);
        int n = cnt[node];
        int s = cursor[node] - n;
        int k = 0;
        for (; k + 7 < n; k += 8) {
            int r0 = eidx[s + k + 0], r1 = eidx[s + k + 1];
            int r2 = eidx[s + k + 2], r3 = eidx[s + k + 3];
            int r4 = eidx[s + k + 4], r5 = eidx[s + k + 5];
            int r6 = eidx[s + k + 6], r7 = eidx[s + k + 7];
            unsigned v0 = xh[((size_t)r0 << 6) + lane];
            unsigned v1 = xh[((size_t)r1 << 6) + lane];
            unsigned v2 = xh[((size_t)r2 << 6) + lane];
            unsigned v3 = xh[((size_t)r3 << 6) + lane];
            unsigned v4 = xh[((size_t)r4 << 6) + lane];
            unsigned v5 = xh[((size_t)r5 << 6) + lane];
            unsigned v6 = xh[((size_t)r6 << 6) + lane];
            unsigned v7 = xh[((size_t)r7 << 6) + lane];
            a0 += bflo(v0); a1 += bfhi(v0);
            a0 += bflo(v1); a1 += bfhi(v1);
            a0 += bflo(v2); a1 += bfhi(v2);
            a0 += bflo(v3); a1 += bfhi(v3);
            a0 += bflo(v4); a1 += bfhi(v4);
            a0 += bflo(v5); a1 += bfhi(v5);
            a0 += bflo(v6); a1 += bfhi(v6);
            a0 += bflo(v7); a1 += bfhi(v7);
        }
        for (; k + 3 < n; k += 4) {
            int r0 = eidx[s + k + 0], r1 = eidx[s + k + 1];
            int r2 = eidx[s + k + 2], r3 = eidx[s + k + 3];
            unsigned v0 = xh[((size_t)r0 << 6) + lane];
            unsigned v1 = xh[((size_t)r1 << 6) + lane];
            unsigned v2 = xh[((size_t)r2 << 6) + lane];
            unsigned v3 = xh[((size_t)r3 << 6) + lane];
            a0 += bflo(v0); a1 += bfhi(v0);
            a0 += bflo(v1); a1 += bfhi(v1);
            a0 += bflo(v2); a1 += bfhi(v2);
            a0 += bflo(v3); a1 += bfhi(v3);
        }
        for (; k < n; ++k) {
            unsigned v0 = xh[((size_t)eidx[s + k] << 6) + lane];
            a0 += bflo(v0); a1 += bfhi(v0);
        }
        float d = dinv[node];
        ash[lrow][lane] = (unsigned)f2bf(a0 * d) | ((unsigned)f2bf(a1 * d) << 16);
    }

    // ---- phase 2: GEMM1 (A from own-wave LDS rows; dep visible via uint4) ----
    const int m = lane & 15, q = lane >> 4;
    f32x4 acc[16];
#pragma unroll
    for (int c = 0; c < 16; ++c) acc[c] = (f32x4){0.f, 0.f, 0.f, 0.f};

#pragma unroll
    for (int s = 0; s < 4; ++s) {           // k = 32s + 8q + j
        uint4 t = *(const uint4*)&ash[wave * 16 + m][s * 16 + q * 4];
        bf16x8 a = __builtin_bit_cast(bf16x8, t);
        const __hip_bfloat16* bp = W1p + ((size_t)(4 * s + q) * F2) * 8;
#pragma unroll
        for (int c = 0; c < 16; ++c) {
            bf16x8 b = *(const bf16x8*)(bp + ((size_t)(c * 16 + m) << 3));
            acc[c] = __builtin_amdgcn_mfma_f32_16x16x32_bf16(a, b, acc[c], 0, 0, 0);
        }
    }

    __syncthreads();                        // guard ash -> h overlay (type-aliased)
    __hip_bfloat16* hs = (__hip_bfloat16*)ash;   // row stride 264 bf16 = 528 B
#pragma unroll
    for (int c = 0; c < 16; ++c) {
        int col = c * 16 + m;
        float bj = b1[col];
#pragma unroll
        for (int r = 0; r < 4; ++r) {
            int lr = wave * 16 + q * 4 + r;
            hs[lr * 264 + col] = __float2bfloat16(fmaxf(acc[c][r] + bj, 0.0f));
        }
    }
    __syncthreads();

    f32x4 acc2[3];
#pragma unroll
    for (int c = 0; c < 3; ++c) acc2[c] = (f32x4){0.f, 0.f, 0.f, 0.f};

#pragma unroll
    for (int s = 0; s < 8; ++s) {
        bf16x8 a = *(const bf16x8*)&hs[(wave * 16 + m) * 264 + s * 32 + q * 8];
        const __hip_bfloat16* bp = W2p + ((size_t)(4 * s + q) * 48) * 8;
#pragma unroll
        for (int c = 0; c < 3; ++c) {
            bf16x8 b = *(const bf16x8*)(bp + ((size_t)(c * 16 + m) << 3));
            acc2[c] = __builtin_amdgcn_mfma_f32_16x16x32_bf16(a, b, acc2[c], 0, 0, 0);
        }
    }

#pragma unroll
    for (int c = 0; c < 3; ++c) {
        int col = c * 16 + m;
        if (col < F3) {
#pragma unroll
            for (int r = 0; r < 4; ++r) {
                int grow = i0 + wave * 16 + q * 4 + r;
                if (grow < NN)
                    tg[(size_t)grow * F3 + col] = f2bf(acc2[c][r] * dinv[grow]);
            }
        }
    }
}

// ---- layer-2 pull aggregation: 2 nodes/wave, dword-per-lane over packed 80B rows ----
__global__ __launch_bounds__(256) void k_agg2(const int* __restrict__ cursor,
                                              const int* __restrict__ cnt,
                                              const int* __restrict__ eidx,
                                              const float* __restrict__ dinv,
                                              const unsigned short* __restrict__ tg,
                                              const float* __restrict__ b2,
                                              float* __restrict__ out) {
    const int wave = threadIdx.x >> 6;
    const int lane = threadIdx.x & 63;
    const int h = lane >> 5;                        // which node of the pair
    const int t = lane & 31;                        // dword index in row (t<20 active)
    const int node = blockIdx.x * 8 + wave * 2 + h; // NN%8==0 -> always valid
    const unsigned* __restrict__ tgw = (const unsigned*)tg;
    if (t >= 20) return;                            // 80B row = 20 dwords

    unsigned vs = tgw[(size_t)node * 20 + t];       // self term
    float a0 = bflo(vs), a1 = bfhi(vs);
    const int n = cnt[node];
    const int s = cursor[node] - n;
    int k = 0;
    for (; k + 7 < n; k += 8) {
        int r0 = eidx[s + k + 0], r1 = eidx[s + k + 1];
        int r2 = eidx[s + k + 2], r3 = eidx[s + k + 3];
        int r4 = eidx[s + k + 4], r5 = eidx[s + k + 5];
        int r6 = eidx[s + k + 6], r7 = eidx[s + k + 7];
        unsigned v0 = tgw[(size_t)r0 * 20 + t];
        unsigned v1 = tgw[(size_t)r1 * 20 + t];
        unsigned v2 = tgw[(size_t)r2 * 20 + t];
        unsigned v3 = tgw[(size_t)r3 * 20 + t];
        unsigned v4 = tgw[(size_t)r4 * 20 + t];
        unsigned v5 = tgw[(size_t)r5 * 20 + t];
        unsigned v6 = tgw[(size_t)r6 * 20 + t];
        unsigned v7 = tgw[(size_t)r7 * 20 + t];
        a0 += bflo(v0); a1 += bfhi(v0);
        a0 += bflo(v1); a1 += bfhi(v1);
        a0 += bflo(v2); a1 += bfhi(v2);
        a0 += bflo(v3); a1 += bfhi(v3);
        a0 += bflo(v4); a1 += bfhi(v4);
        a0 += bflo(v5); a1 += bfhi(v5);
        a0 += bflo(v6); a1 += bfhi(v6);
        a0 += bflo(v7); a1 += bfhi(v7);
    }
    for (; k + 3 < n; k += 4) {
        int r0 = eidx[s + k + 0], r1 = eidx[s + k + 1];
        int r2 = eidx[s + k + 2], r3 = eidx[s + k + 3];
        unsigned v0 = tgw[(size_t)r0 * 20 + t];
        unsigned v1 = tgw[(size_t)r1 * 20 + t];
        unsigned v2 = tgw[(size_t)r2 * 20 + t];
        unsigned v3 = tgw[(size_t)r3 * 20 + t];
        a0 += bflo(v0); a1 += bfhi(v0);
        a0 += bflo(v1); a1 += bfhi(v1);
        a0 += bflo(v2); a1 += bfhi(v2);
        a0 += bflo(v3); a1 += bfhi(v3);
    }
    for (; k < n; ++k) {
        unsigned v0 = tgw[(size_t)eidx[s + k] * 20 + t];
        a0 += bflo(v0); a1 += bfhi(v0);
    }
    float d = dinv[node];
    float2 bb = ((const float2*)b2)[t];
    float2 o;
    o.x = a0 * d + bb.x;
    o.y = a1 * d + bb.y;
    ((float2*)(out + (size_t)node * F3))[t] = o;
}

extern "C" void kernel_launch(void* const* d_in, const int* in_sizes, int n_in,
                              void* d_out, int out_size, void* d_ws, size_t ws_size,
                              hipStream_t stream) {
    const float* x  = (const float*)d_in[0];
    const int*   ei = (const int*)d_in[1];
    const float* W1 = (const float*)d_in[2];
    const float* b1 = (const float*)d_in[3];
    const float* W2 = (const float*)d_in[4];
    const float* b2 = (const float*)d_in[5];
    float* out = (float*)d_out;

    const int* row = ei;
    const int* col = ei + EE;

    // ws: cnt[N] | cursor[N] | dinv[N] | hist[NBUK*NBLK] | bintot | binbase |
    //     done | eidx[E] | xh[N*64 u32] | rec-region (25.6MB) | W1p | W2p
    // overlays: tg (N*40 bf16 packed 80B rows, 8MB) on rec (dead after k_csr).
    // NOTE: tg must NOT overlay xh — k_aggemm reads all of xh (random gather)
    // while writing tg (round-4 bug).
    int* cnt     = (int*)d_ws;
    int* cursor  = cnt + NN;
    float* dinv  = (float*)(cursor + NN);
    int* hist    = (int*)(dinv + NN);
    int* bintot  = hist + NBUK * NBLK;
    int* binbase = bintot + NBUK;
    int* done    = binbase + NBUK + 1;         // slack[0]
    int* eidx    = binbase + (NBUK + 1) + 9;   // alignment slack -> xh % 16 == 0
    unsigned* xh  = (unsigned*)(eidx + EE);
    unsigned* rec = xh + (size_t)NN * 64;              // 25.6MB region
    unsigned short* tg = (unsigned short*)rec;         // overlay on dead rec (8MB)
    __hip_bfloat16* W1p = (__hip_bfloat16*)(rec + (size_t)NN * 64);
    __hip_bfloat16* W2p = W1p + (size_t)F1 * F2;

    k_hist   <<<NBLK, 256, 0, stream>>>(col, hist, done);
    k_scanbin<<<NBUK, 512, 0, stream>>>(hist, bintot, binbase, done);
    k_scat   <<<NBLK, 256, 0, stream>>>(row, col, hist, binbase, rec);
    k_csr    <<<NBUK, 256, 0, stream>>>(binbase, rec, eidx, cnt, cursor, dinv);

    k_prep<<<XB2 + (F1 * F2 + F2 * 48 + 255) / 256, 256, 0, stream>>>(
        (const float4*)x, dinv, (uint2*)xh, W1, W2, W1p, W2p);

    k_aggemm<<<(NN + MROWS - 1) / MROWS, 256, 0, stream>>>(
        cursor, cnt, eidx, dinv, xh, W1p, b1, W2p, tg);
    k_agg2<<<NN / 8, 256, 0, stream>>>(cursor, cnt, eidx, dinv, tg, b2, out);
}